// Round 4
// baseline (155.138 us; speedup 1.0000x reference)
//
#include <hip/hip_runtime.h>

#define H_IMG 1080
#define W_IMG 1920
#define HW_PIX (H_IMG * W_IMG)
#define GY 16
#define GX 16
#define GL 8
#define CF 12          // floats per grid cell
#define SEG 320        // pixels per segment; 1920 = 6*320 exactly
#define SPR 6          // segments per row
#define NSEG (H_IMG * SPR)   // 6480
#define NBLK 1536      // 6 blocks/CU * 256 CUs -> fully resident, persistent

typedef float v4f __attribute__((ext_vector_type(4)));  // builtin-compatible

// R3: persistent-block version. R1 (dense LDS-transposed stores) and R2
// (SEG=320, direct loads) were both near-neutral: the kernel (~71us) is
// dominated neither by traffic (149MB ~ 22us @ 6.8TB/s) nor compute (~4us)
// nor occupancy (30 waves/CU). Remaining suspect: 6480 short-lived blocks =
// ~25 sequential generations/CU, each paying launch + latency ramp + 2
// barriers + store-drain-before-retire (~1.8us exposed per generation).
// Fix: 1536 resident blocks grid-stride over segments; next segment's rgb
// loads are issued BEFORE the current barrier (a full segment of latency
// cover); stores are nontemporal (output never re-read; keep L2/L3 for rgb).
//
// Per segment: y-interp is uniform per row; a 320-px span covers exactly
// grid x-cells xc0..xc0+3. Stage G'[xi][z][c] = lerp_y(grid) in LDS
// (4*8*3 float4 = 1.5KB); each pixel does 4 LDS cells instead of 8 global.
__global__ __launch_bounds__(SEG) void bg_kernel(
    const float* __restrict__ rgb,    // (3, H, W)
    const float* __restrict__ grids,  // (NUM, 16, 16, 8, 12)
    const int* __restrict__ idxp,
    float* __restrict__ out)          // [affine HW*12 | res HW*3]
{
    __shared__ float4 sg[96];            // [xi(4)][z(8)][c4(3)]  1.5 KB
    __shared__ float  s_aff[SEG * 12];   // affine out, pix-major 15 KB
    __shared__ float  s_res[SEG * 3];    // res out, pix-major    3.75 KB

    const int tid = threadIdx.x;
    const float* grid = grids + (size_t)idxp[0] * (GY * GX * GL * CF);

    int s = blockIdx.x;                  // first segment for this block

    // ---- prologue: issue rgb loads for the first segment ----
    int y = s / SPR;
    int xb = (s - y * SPR) * SEG;
    int p = y * W_IMG + xb + tid;
    float r = rgb[p];
    float g = rgb[HW_PIX + p];
    float b = rgb[2 * HW_PIX + p];

    while (s < NSEG) {
        const int snext = s + NBLK;
        y  = s / SPR;
        xb = (s - y * SPR) * SEG;
        const int p0 = y * W_IMG + xb;   // multiple of 320 -> float4-aligned
        const int x  = xb + tid;

        // ---- stage y-lerped grid cells for this row/span ----
        float gyv = (float)y * (15.0f / 1079.0f);
        float fy = floorf(gyv);
        float wy = gyv - fy;
        int y0 = min(max((int)fy, 0), GY - 1);
        int y1 = min(y0 + 1, GY - 1);
        int xc0 = (int)floorf((float)xb * (15.0f / 1919.0f));

        if (tid < 96) {
            int xi  = tid / 24;
            int rem = tid - xi * 24;
            int z   = rem / 3;
            int c4  = rem - z * 3;
            int xc  = min(xc0 + xi, GX - 1);
            const float4* c0 = (const float4*)(grid + (size_t)((y0 * GX + xc) * GL + z) * CF) + c4;
            const float4* c1 = (const float4*)(grid + (size_t)((y1 * GX + xc) * GL + z) * CF) + c4;
            float4 a = *c0, bb = *c1;
            float wy0 = 1.0f - wy;
            float4 rr;
            rr.x = wy0 * a.x + wy * bb.x;
            rr.y = wy0 * a.y + wy * bb.y;
            rr.z = wy0 * a.z + wy * bb.z;
            rr.w = wy0 * a.w + wy * bb.w;
            sg[tid] = rr;
        }

        // ---- issue NEXT segment's rgb loads: a full segment to cover HBM ----
        float rn = 0.0f, gn = 0.0f, bn = 0.0f;
        if (snext < NSEG) {
            int yn  = snext / SPR;
            int xbn = (snext - yn * SPR) * SEG;
            int pn  = yn * W_IMG + xbn + tid;
            rn = rgb[pn];
            gn = rgb[HW_PIX + pn];
            bn = rgb[2 * HW_PIX + pn];
        }

        __syncthreads();   // sg ready; prev drain-reads of s_aff/s_res done

        float gray = 0.299f * r + 0.587f * g + 0.114f * b;

        float gxv = (float)x * (15.0f / 1919.0f);
        float fx = floorf(gxv), wx = gxv - fx;
        float gz = fminf(fmaxf(gray, 0.0f), 1.0f) * 7.0f;
        float fz = floorf(gz), wz = gz - fz;

        int x0g = min(max((int)fx, 0), GX - 1);
        int x1g = min(x0g + 1, GX - 1);
        int xi0 = x0g - xc0;                // in [0,3]
        int xi1 = x1g - xc0;                // in [0,3]
        int z0 = min(max((int)fz, 0), GL - 1);
        int z1 = min(z0 + 1, GL - 1);

        float w00 = (1.0f - wx) * (1.0f - wz);
        float w01 = (1.0f - wx) * wz;
        float w10 = wx * (1.0f - wz);
        float w11 = wx * wz;

        const float4* A = sg + (xi0 * 24 + z0 * 3);
        const float4* B = sg + (xi0 * 24 + z1 * 3);
        const float4* C = sg + (xi1 * 24 + z0 * 3);
        const float4* D = sg + (xi1 * 24 + z1 * 3);

        float4 acc[3];
#pragma unroll
        for (int j = 0; j < 3; ++j) {
            float4 va = A[j], vb = B[j], vc = C[j], vd = D[j];
            float4 o;
            o.x = fmaf(w00, va.x, fmaf(w01, vb.x, fmaf(w10, vc.x, w11 * vd.x)));
            o.y = fmaf(w00, va.y, fmaf(w01, vb.y, fmaf(w10, vc.y, w11 * vd.y)));
            o.z = fmaf(w00, va.z, fmaf(w01, vb.z, fmaf(w10, vc.z, w11 * vd.z)));
            o.w = fmaf(w00, va.w, fmaf(w01, vb.w, fmaf(w10, vc.w, w11 * vd.w)));
            acc[j] = o;
        }

        // ---- outputs to LDS (pix-major = global layout order) ----
        float4* sa = (float4*)(s_aff + tid * 12);   // 48B-aligned
        sa[0] = acc[0];
        sa[1] = acc[1];
        sa[2] = acc[2];

        // res_rgb = A[:, :3] @ rgb + A[:, 3]
        s_res[tid * 3 + 0] = fmaf(acc[0].x, r, fmaf(acc[0].y, g, fmaf(acc[0].z, b, acc[0].w)));
        s_res[tid * 3 + 1] = fmaf(acc[1].x, r, fmaf(acc[1].y, g, fmaf(acc[1].z, b, acc[1].w)));
        s_res[tid * 3 + 2] = fmaf(acc[2].x, r, fmaf(acc[2].y, g, fmaf(acc[2].z, b, acc[2].w)));

        __syncthreads();

        // ---- dense drain: 16B/lane, nontemporal (output never re-read) ----
        const v4f* sa4 = (const v4f*)s_aff;              // 960 v4f
        v4f* ao = (v4f*)(out + (size_t)p0 * 12);         // 15360 B contiguous
        __builtin_nontemporal_store(sa4[tid],           ao + tid);
        __builtin_nontemporal_store(sa4[tid + SEG],     ao + tid + SEG);
        __builtin_nontemporal_store(sa4[tid + 2 * SEG], ao + tid + 2 * SEG);

        if (tid < 240) {                                  // 3840 B contiguous
            v4f* ro = (v4f*)(out + (size_t)HW_PIX * 12 + (size_t)p0 * 3);
            __builtin_nontemporal_store(((const v4f*)s_res)[tid], ro + tid);
        }

        r = rn; g = gn; b = bn;
        s = snext;
    }
}

extern "C" void kernel_launch(void* const* d_in, const int* in_sizes, int n_in,
                              void* d_out, int out_size, void* d_ws, size_t ws_size,
                              hipStream_t stream) {
    const float* rgb   = (const float*)d_in[0];
    const float* grids = (const float*)d_in[1];
    const int*   idx   = (const int*)d_in[2];
    float*       out   = (float*)d_out;

    dim3 grid(NBLK);      // persistent: 6 resident blocks/CU * 256 CUs
    dim3 block(SEG);
    bg_kernel<<<grid, block, 0, stream>>>(rgb, grids, idx, out);
}

// Round 5
// 150.055 us; speedup vs baseline: 1.0339x; 1.0339x over previous
//
#include <hip/hip_runtime.h>

#define H_IMG 1080
#define W_IMG 1920
#define HW_PIX (H_IMG * W_IMG)
#define GY 16
#define GX 16
#define GL 8
#define CF 12          // floats per grid cell
#define SEG 320        // pixels per block (5 waves); 1920 = 6*320 exactly

typedef float v4f __attribute__((ext_vector_type(4)));  // nontemporal-builtin-compatible

// R5: identical to R2 (best, 144.9us) except the 4 drain stores are
// __builtin_nontemporal_store (MUBUF nt: no-allocate in L2). Single-variable
// probe of the write-allocate/RFO theory: kernel moves 149MB but runs at
// ~2.1TB/s; if TCC fetches output lines on store miss, true traffic is
// ~273MB, matching the observed time. R3/R4's persistent-loop conflated this
// (its prefetch was drained by the very next barrier and each barrier waited
// on the previous iteration's stores -> regression; reverted).
__global__ __launch_bounds__(SEG) void bg_kernel(
    const float* __restrict__ rgb,    // (3, H, W)
    const float* __restrict__ grids,  // (NUM, 16, 16, 8, 12)
    const int* __restrict__ idxp,
    float* __restrict__ out)          // [affine HW*12 | res HW*3]
{
    __shared__ float4 sg[96];            // [xi(4)][z(8)][c4(3)]  1.5 KB
    __shared__ float  s_aff[SEG * 12];   // affine out, pix-major 15 KB
    __shared__ float  s_res[SEG * 3];    // res out, pix-major    3.75 KB

    const int tid = threadIdx.x;
    const int y = blockIdx.y;
    const int xbase = blockIdx.x * SEG;
    const int p0 = y * W_IMG + xbase;    // multiple of 320 -> float4-aligned
    const int x = xbase + tid;
    const int p = p0 + tid;

    // ---- issue pixel loads FIRST: latency hides under grid staging ----
    float r = rgb[p];
    float g = rgb[HW_PIX + p];
    float b = rgb[2 * HW_PIX + p];

    const float* grid = grids + (size_t)idxp[0] * (GY * GX * GL * CF);

    // row-uniform y interpolation
    float gyv = (float)y * (15.0f / 1079.0f);
    float fy = floorf(gyv);
    float wy = gyv - fy;
    int y0 = min(max((int)fy, 0), GY - 1);
    int y1 = min(y0 + 1, GY - 1);

    // block-uniform first x-cell
    int xc0 = (int)floorf((float)xbase * (15.0f / 1919.0f));

    if (tid < 96) {
        int xi  = tid / 24;
        int rem = tid - xi * 24;
        int z   = rem / 3;
        int c4  = rem - z * 3;
        int xc  = min(xc0 + xi, GX - 1);
        const float4* c0 = (const float4*)(grid + (size_t)((y0 * GX + xc) * GL + z) * CF) + c4;
        const float4* c1 = (const float4*)(grid + (size_t)((y1 * GX + xc) * GL + z) * CF) + c4;
        float4 a = *c0, bb = *c1;
        float wy0 = 1.0f - wy;
        float4 rr;
        rr.x = wy0 * a.x + wy * bb.x;
        rr.y = wy0 * a.y + wy * bb.y;
        rr.z = wy0 * a.z + wy * bb.z;
        rr.w = wy0 * a.w + wy * bb.w;
        sg[tid] = rr;
    }
    __syncthreads();

    float gray = 0.299f * r + 0.587f * g + 0.114f * b;

    float gxv = (float)x * (15.0f / 1919.0f);
    float fx = floorf(gxv), wx = gxv - fx;
    float gz = fminf(fmaxf(gray, 0.0f), 1.0f) * 7.0f;
    float fz = floorf(gz), wz = gz - fz;

    int x0g = min(max((int)fx, 0), GX - 1);
    int x1g = min(x0g + 1, GX - 1);
    int xi0 = x0g - xc0;                // in [0,3]
    int xi1 = x1g - xc0;                // in [0,3]
    int z0 = min(max((int)fz, 0), GL - 1);
    int z1 = min(z0 + 1, GL - 1);

    float w00 = (1.0f - wx) * (1.0f - wz);
    float w01 = (1.0f - wx) * wz;
    float w10 = wx * (1.0f - wz);
    float w11 = wx * wz;

    const float4* A = sg + (xi0 * 24 + z0 * 3);
    const float4* B = sg + (xi0 * 24 + z1 * 3);
    const float4* C = sg + (xi1 * 24 + z0 * 3);
    const float4* D = sg + (xi1 * 24 + z1 * 3);

    float4 acc[3];
#pragma unroll
    for (int j = 0; j < 3; ++j) {
        float4 va = A[j], vb = B[j], vc = C[j], vd = D[j];
        float4 o;
        o.x = fmaf(w00, va.x, fmaf(w01, vb.x, fmaf(w10, vc.x, w11 * vd.x)));
        o.y = fmaf(w00, va.y, fmaf(w01, vb.y, fmaf(w10, vc.y, w11 * vd.y)));
        o.z = fmaf(w00, va.z, fmaf(w01, vb.z, fmaf(w10, vc.z, w11 * vd.z)));
        o.w = fmaf(w00, va.w, fmaf(w01, vb.w, fmaf(w10, vc.w, w11 * vd.w)));
        acc[j] = o;
    }

    // ---- outputs to LDS (pix-major = global layout order) ----
    float4* sa = (float4*)(s_aff + tid * 12);   // 48B-aligned
    sa[0] = acc[0];
    sa[1] = acc[1];
    sa[2] = acc[2];

    // res_rgb = A[:, :3] @ rgb + A[:, 3]
    s_res[tid * 3 + 0] = fmaf(acc[0].x, r, fmaf(acc[0].y, g, fmaf(acc[0].z, b, acc[0].w)));
    s_res[tid * 3 + 1] = fmaf(acc[1].x, r, fmaf(acc[1].y, g, fmaf(acc[1].z, b, acc[1].w)));
    s_res[tid * 3 + 2] = fmaf(acc[2].x, r, fmaf(acc[2].y, g, fmaf(acc[2].z, b, acc[2].w)));

    __syncthreads();

    // ---- dense drain: 16B/lane, nontemporal (no L2 write-allocate) ----
    const v4f* sa4 = (const v4f*)s_aff;              // 960 v4f
    v4f* ao = (v4f*)(out + (size_t)p0 * 12);         // 15360 B contiguous
    __builtin_nontemporal_store(sa4[tid],           ao + tid);
    __builtin_nontemporal_store(sa4[tid + SEG],     ao + tid + SEG);
    __builtin_nontemporal_store(sa4[tid + 2 * SEG], ao + tid + 2 * SEG);

    if (tid < 240) {                                  // 3840 B contiguous
        v4f* ro = (v4f*)(out + (size_t)HW_PIX * 12 + (size_t)p0 * 3);
        __builtin_nontemporal_store(((const v4f*)s_res)[tid], ro + tid);
    }
}

extern "C" void kernel_launch(void* const* d_in, const int* in_sizes, int n_in,
                              void* d_out, int out_size, void* d_ws, size_t ws_size,
                              hipStream_t stream) {
    const float* rgb   = (const float*)d_in[0];
    const float* grids = (const float*)d_in[1];
    const int*   idx   = (const int*)d_in[2];
    float*       out   = (float*)d_out;

    dim3 grid(W_IMG / SEG, H_IMG);   // (6, 1080)
    dim3 block(SEG);
    bg_kernel<<<grid, block, 0, stream>>>(rgb, grids, idx, out);
}